// Round 6
// baseline (1410.294 us; speedup 1.0000x reference)
//
#include <hip/hip_runtime.h>
#include <cstdint>
#include <cstddef>

#define BATCH       65536
#define LDSW        36          // padded LDS row stride for tiny-kernel matrices
#define NCHEB       26          // Chebyshev terms for log on [CALPHA, CBETA]
#define CALPHA      0.2f
#define CBETA       6.0f
#define NS_ITERS    6           // Newton-Schulz sqrt iterations
#define EXP_TERMS   12          // Taylor terms for matrix exp
#define GRID_B      4096        // kB/kC: 16 blocks/CU  (bounds(64,4))
#define GRID_C      4096
#define GRID_D      5120        // kD: 20 blocks/CU     (bounds(64,5))

// ws float offsets
#define OFF_MEAN0   0
#define OFF_INVS0   1024
#define OFF_S0      2048
#define OFF_LOGAVG  3072
#define OFF_INVS    4096
#define OFF_SSQRT   5120
#define OFF_VAR     6144
#define OFF_P       6145
#define OFF_CHEB    6152        // 26 floats

typedef float (*LdsMat)[LDSW];
typedef __attribute__((ext_vector_type(8))) short          short8;
typedef __attribute__((ext_vector_type(4))) float          f32x4;
typedef __attribute__((ext_vector_type(4))) unsigned short us4;
typedef unsigned short u16t;
typedef unsigned int   u32t;

#define MFMA16(a, b, c) __builtin_amdgcn_mfma_f32_16x16x32_bf16((a), (b), (c), 0, 0, 0)

// ---------------- bf16 pack / split helpers (perm-based, round-4-proven) ----------------
// pack2_rn: [bf16_rn(b) | bf16_rn(a)] in one dword
__device__ __forceinline__ u32t pack2_rn(float a, float b) {
  u32t ua = __float_as_uint(a) + 0x8000u;
  u32t ub = __float_as_uint(b) + 0x8000u;
  return __builtin_amdgcn_perm(ub, ua, 0x07060302u);
}
// split2: hi = rn-bf16 pair (dword), lo = truncated-bf16 pair of the residual
__device__ __forceinline__ void split2(float a, float b, u32t& hw, u32t& lw) {
  u32t ua = __float_as_uint(a) + 0x8000u;
  u32t ub = __float_as_uint(b) + 0x8000u;
  hw = __builtin_amdgcn_perm(ub, ua, 0x07060302u);
  float ra = a - __uint_as_float(ua & 0xFFFF0000u);
  float rb = b - __uint_as_float(ub & 0xFFFF0000u);
  lw = __builtin_amdgcn_perm(__float_as_uint(rb), __float_as_uint(ra), 0x07060302u);
}

// Staged matrices: u16 [32][40] col-major (G[col][row] = bf16 of M[row][col]).
// Fragment read: 8 contiguous values along k at column 16t+c15, k0 = 8g (16B aligned,
// row stride 80 B -> bank-quad (5*c15+g) mod 8, conflict-light). Round-4-proven.
__device__ __forceinline__ short8 fragr(const u16t (*G)[40], int t, int c15, int g) {
  return *reinterpret_cast<const short8*>(&G[16 * t + c15][8 * g]);
}
// Stage one C-layout tile (4 f32, rows 16i+4g..+3, col 16j+c15), single-bf16
__device__ __forceinline__ void stg_single(u16t (*G)[40], int col, int row, f32x4 v) {
  uint2 w; w.x = pack2_rn(v[0], v[1]); w.y = pack2_rn(v[2], v[3]);
  *reinterpret_cast<uint2*>(&G[col][row]) = w;
}
__device__ __forceinline__ void stg_split(u16t (*Gh)[40], u16t (*Gl)[40], int col, int row, f32x4 v) {
  u32t h0, l0, h1, l1;
  split2(v[0], v[1], h0, l0);
  split2(v[2], v[3], h1, l1);
  uint2 hv; hv.x = h0; hv.y = h1;
  uint2 lv; lv.x = l0; lv.y = l1;
  *reinterpret_cast<uint2*>(&Gh[col][row]) = hv;
  *reinterpret_cast<uint2*>(&Gl[col][row]) = lv;
}
// load 8 consecutive f32 from global (one A-frag row slice of a SYMMETRIC matrix),
// scale, split into hi/lo bf16 fragments
__device__ __forceinline__ void ldsplit8(const float* p, float mul, short8& hi, short8& lo) {
  float4 a = *reinterpret_cast<const float4*>(p);
  float4 b = *reinterpret_cast<const float4*>(p + 4);
  u32t h0, l0, h1, l1, h2, l2, h3, l3;
  split2(a.x * mul, a.y * mul, h0, l0);
  split2(a.z * mul, a.w * mul, h1, l1);
  split2(b.x * mul, b.y * mul, h2, l2);
  split2(b.z * mul, b.w * mul, h3, l3);
  union { uint4 u; short8 s; } uh, ul;
  uh.u.x = h0; uh.u.y = h1; uh.u.z = h2; uh.u.w = h3;
  ul.u.x = l0; ul.u.y = l1; ul.u.z = l2; ul.u.w = l3;
  hi = uh.s; lo = ul.s;
}

// scalar split for cold-path frag loads
__device__ __forceinline__ void splitf(float a, u16t& h, u16t& l) {
  unsigned u  = __float_as_uint(a);
  unsigned uh = (u + 0x8000u) & 0xFFFF0000u;
  float    r  = a - __uint_as_float(uh);
  unsigned ul = __float_as_uint(r) + 0x8000u;
  h = (u16t)(uh >> 16);
  l = (u16t)(ul >> 16);
}
__device__ __forceinline__ void load_sym_frags(const float* base, int c15, int g,
                                               short8* Fh, short8* Fl) {
#pragma unroll
  for (int t = 0; t < 2; ++t) {
    const float* sp = base + (16 * t + c15) * 32 + 8 * g;
    short8 hh, ll;
#pragma unroll
    for (int j = 0; j < 8; ++j) {
      u16t h, l;
      splitf(sp[j], h, l);
      hh[j] = (short)h;
      ll[j] = (short)l;
    }
    Fh[t] = hh;
    Fl[t] = ll;
  }
}

// ---------------- MFMA whiten + forward-Chebyshev log core (round-4 math) ----------------
// L = cheb_log( GSC*(S x S) - MSH*I ).  A-side (2*Ytilde) split hi/lo in regs;
// recurrence B-operand (T_{k-1}) single rn-bf16 via ping-pong LDS (Bu <-> H).
template <bool ACCUM>
__device__ __forceinline__ void whiten_cheb(
    const float* __restrict__ xb, const short8* S_h, const short8* S_l,
    u16t (*H)[40], u16t (*Lo)[40], u16t (*Bu)[40],
    const float* __restrict__ cof, int g, int c15, const f32x4& dg4, f32x4 (&L)[2][2]) {
  const f32x4 z4 = {0.f, 0.f, 0.f, 0.f};
  // 1. X A-frags straight from global (X symmetric)
  short8 Xa_h[2], Xa_l[2];
#pragma unroll
  for (int t = 0; t < 2; ++t)
    ldsplit8(xb + (16 * t + c15) * 32 + 8 * g, 1.0f, Xa_h[t], Xa_l[t]);
  // 2. V2 = X * S  -> split staged into H/Lo
  f32x4 acc[2][2];
#pragma unroll
  for (int i = 0; i < 2; ++i)
#pragma unroll
    for (int j = 0; j < 2; ++j) {
      f32x4 a = z4;
      a = MFMA16(Xa_l[i], S_h[j], a);
      a = MFMA16(Xa_h[i], S_l[j], a);
      a = MFMA16(Xa_h[i], S_h[j], a);
      acc[i][j] = a;
    }
#pragma unroll
  for (int i = 0; i < 2; ++i)
#pragma unroll
    for (int j = 0; j < 2; ++j)
      stg_split(H, Lo, 16 * j + c15, 16 * i + 4 * g, acc[i][j]);
  __syncthreads();
  short8 Vb_h[2], Vb_l[2];
#pragma unroll
  for (int j = 0; j < 2; ++j) {
    Vb_h[j] = fragr(H, j, c15, g);
    Vb_l[j] = fragr(Lo, j, c15, g);
  }
  // 3. Y = S * V2 ; Ytilde = GSC*Y - MSH*I  (= T1)
#pragma unroll
  for (int j = 0; j < 2; ++j)
#pragma unroll
    for (int i = 0; i < 2; ++i) {
      f32x4 a = z4;
      a = MFMA16(S_l[i], Vb_h[j], a);
      a = MFMA16(S_h[i], Vb_l[j], a);
      a = MFMA16(S_h[i], Vb_h[j], a);
      acc[i][j] = a;
    }
  const float GSC = 2.f / (CBETA - CALPHA);
  const float MSH = (CALPHA + CBETA) / (CBETA - CALPHA);
  const float c0 = cof[0], c1 = cof[1];
  f32x4 nTm2[2][2], accB[2][2];
#pragma unroll
  for (int i = 0; i < 2; ++i)
#pragma unroll
    for (int j = 0; j < 2; ++j)
#pragma unroll
      for (int r = 0; r < 4; ++r) {
        float dgf = (i == j) ? dg4[r] : 0.f;
        float yt  = fmaf(acc[i][j][r], GSC, -MSH * dgf);     // T1
        accB[i][j][r] = yt;
        nTm2[i][j][r] = -dgf;                                 // -T0
        float base = ACCUM ? L[i][j][r] : 0.f;
        L[i][j][r] = fmaf(c1, yt, fmaf(c0, dgf, base));
      }
  __syncthreads();                                            // Vb reads done before overwrite
  // stage A = 2*Ytilde split -> H/Lo ; stage B = T1 single -> Bu
#pragma unroll
  for (int i = 0; i < 2; ++i)
#pragma unroll
    for (int j = 0; j < 2; ++j) {
      f32x4 y2;
#pragma unroll
      for (int r = 0; r < 4; ++r) y2[r] = accB[i][j][r] + accB[i][j][r];
      stg_split(H, Lo, 16 * j + c15, 16 * i + 4 * g, y2);
      stg_single(Bu, 16 * j + c15, 16 * i + 4 * g, accB[i][j]);
    }
  __syncthreads();
  short8 Ya_h[2], Ya_l[2];
#pragma unroll
  for (int t = 0; t < 2; ++t) {
    Ya_h[t] = fragr(H, t, c15, g);
    Ya_l[t] = fragr(Lo, t, c15, g);
  }
  // 4. forward pairs: T_k = MFMA(2*Ytilde, bf16(T_{k-1}), -T_{k-2}); L += c_k T_k
  //    ping-pong: read Bu -> write H ; read H -> write Bu  (Ya already in regs)
  f32x4 accA[2][2];
#pragma unroll
  for (int kk = 2; kk < NCHEB; kk += 2) {
    const float cka = cof[kk];
#pragma unroll
    for (int j = 0; j < 2; ++j) {
      short8 B0 = fragr(Bu, j, c15, g);
#pragma unroll
      for (int i = 0; i < 2; ++i) {
        f32x4 a = nTm2[i][j];
        a = MFMA16(Ya_l[i], B0, a);
        a = MFMA16(Ya_h[i], B0, a);
        accA[i][j] = a;
      }
    }
#pragma unroll
    for (int i = 0; i < 2; ++i)
#pragma unroll
      for (int j = 0; j < 2; ++j) {
#pragma unroll
        for (int r = 0; r < 4; ++r) {
          L[i][j][r]    = fmaf(cka, accA[i][j][r], L[i][j][r]);
          nTm2[i][j][r] = -accB[i][j][r];
        }
        stg_single(H, 16 * j + c15, 16 * i + 4 * g, accA[i][j]);
      }
    __syncthreads();
    const float ckb = cof[kk + 1];
#pragma unroll
    for (int j = 0; j < 2; ++j) {
      short8 B1 = fragr(H, j, c15, g);
#pragma unroll
      for (int i = 0; i < 2; ++i) {
        f32x4 a = nTm2[i][j];
        a = MFMA16(Ya_l[i], B1, a);
        a = MFMA16(Ya_h[i], B1, a);
        accB[i][j] = a;
      }
    }
#pragma unroll
    for (int i = 0; i < 2; ++i)
#pragma unroll
      for (int j = 0; j < 2; ++j)
#pragma unroll
        for (int r = 0; r < 4; ++r)
          L[i][j][r] = fmaf(ckb, accB[i][j][r], L[i][j][r]);
    if (kk + 2 < NCHEB) {
#pragma unroll
      for (int i = 0; i < 2; ++i)
#pragma unroll
        for (int j = 0; j < 2; ++j) {
#pragma unroll
          for (int r = 0; r < 4; ++r) nTm2[i][j][r] = -accA[i][j][r];
          stg_single(Bu, 16 * j + c15, 16 * i + 4 * g, accB[i][j]);
        }
      __syncthreads();
    }
  }
  __syncthreads();   // guard: all reads done before next matrix restages H/Lo/Bu
}

// ---------- tiny-kernel helpers (single block, 64 threads; unchanged) ----------

__device__ __forceinline__ float dotrow36(const float* Arow, const float* v) {
  float s = 0.f;
#pragma unroll
  for (int j = 0; j < 8; ++j) {
    float4 a = *reinterpret_cast<const float4*>(Arow + 4 * j);
    s = fmaf(a.x, v[4 * j + 0], s);
    s = fmaf(a.y, v[4 * j + 1], s);
    s = fmaf(a.z, v[4 * j + 2], s);
    s = fmaf(a.w, v[4 * j + 3], s);
  }
  return s;
}

__device__ void mm64(float (*D)[LDSW], const float (*A)[LDSW], const float (*Bm)[LDSW], int lane) {
  const int h = lane >> 5, c = lane & 31;
  float bcol[32];
#pragma unroll
  for (int k = 0; k < 32; ++k) bcol[k] = Bm[k][c];
  float o[16];
#pragma unroll
  for (int i = 0; i < 16; ++i) o[i] = dotrow36(&A[16 * h + i][0], bcol);
  __syncthreads();
#pragma unroll
  for (int i = 0; i < 16; ++i) D[16 * h + i][c] = o[i];
  __syncthreads();
}

__device__ void ns_sqrt(LdsMat& Y, LdsMat& Z, LdsMat& Ya, LdsMat& Za, LdsMat T, int lane) {
  const int h = lane >> 5, c = lane & 31;
  for (int it = 0; it < NS_ITERS; ++it) {
    mm64(T, Z, Y, lane);
#pragma unroll
    for (int i = 0; i < 16; ++i) {
      int r = 16 * h + i;
      T[r][c] = ((r == c) ? 1.5f : 0.f) - 0.5f * T[r][c];
    }
    __syncthreads();
    mm64(Ya, Y, T, lane);
    mm64(Za, T, Z, lane);
    LdsMat t1 = Y; Y = Ya; Ya = t1;
    LdsMat t2 = Z; Z = Za; Za = t2;
  }
}

// ---------- kernels ----------

extern "C" __global__ void __launch_bounds__(256)
spdbn_kA(const float* __restrict__ x, float* __restrict__ wsf) {
  const int e  = (blockIdx.x & 3) * 256 + threadIdx.x;
  const int bs = blockIdx.x >> 2;
  float acc = 0.f;
  for (int t = 0; t < 64; ++t)
    acc += x[(size_t)(bs + 1024 * t) * 1024 + e];
  atomicAdd(&wsf[OFF_MEAN0 + e], acc);
}

extern "C" __global__ void __launch_bounds__(64)
spdbn_kS1(float* __restrict__ wsf) {
  __shared__ alignas(16) float W0[32][LDSW], W1[32][LDSW], W2[32][LDSW], W3[32][LDSW], W4[32][LDSW];
  const int lane = threadIdx.x, h = lane >> 5, c = lane & 31;
  float sacc = 0.f;
#pragma unroll
  for (int k = 0; k < 32; ++k) sacc += wsf[OFF_MEAN0 + 33 * k];
  const float cN = sacc / (32.f * (float)BATCH);
  const float scaleA = 32.f / sacc;
#pragma unroll
  for (int i = 0; i < 16; ++i) {
    int r = 16 * h + i;
    W1[r][c] = wsf[OFF_MEAN0 + r * 32 + c] * scaleA;
    W2[r][c] = (r == c) ? 1.f : 0.f;
  }
  __syncthreads();
  LdsMat Y = W1, Z = W2, Ya = W0, Za = W4;
  ns_sqrt(Y, Z, Ya, Za, W3, lane);
  const float sq = sqrtf(cN), rs = rsqrtf(cN);
#pragma unroll
  for (int i = 0; i < 16; ++i) {
    int r = 16 * h + i;
    wsf[OFF_INVS0 + r * 32 + c] = Z[r][c] * rs;
    wsf[OFF_S0    + r * 32 + c] = Y[r][c] * sq;
  }
  const float PIF = 3.14159265358979f;
  const float th = ((float)lane + 0.5f) * (PIF / 64.f);
  const float t  = 0.5f * (CALPHA + CBETA) + 0.5f * (CBETA - CALPHA) * cosf(th);
  const float fl = logf(t);
  for (int j = 0; j < NCHEB; ++j) {
    float v = fl * cosf((float)j * th) * (2.f / 64.f);
#pragma unroll
    for (int off = 32; off >= 1; off >>= 1) v += __shfl_xor(v, off);
    if (lane == 0) wsf[OFF_CHEB + j] = (j == 0) ? 0.5f * v : v;
  }
}

// Karcher step: accumulate sum_b log(inv_s0 x_b inv_s0)
extern "C" __global__ void __launch_bounds__(64, 4)
spdbn_kB(const float* __restrict__ x, float* __restrict__ wsf) {
  __shared__ alignas(16) u16t H[32][40], Lo[32][40], Bu[32][40];
  const int lane = threadIdx.x;
  const int g = lane >> 4, c15 = lane & 15;
  short8 S_h[2], S_l[2];
  load_sym_frags(wsf + OFF_INVS0, c15, g, S_h, S_l);
  const float* cof = wsf + OFF_CHEB;
  f32x4 dg4;
#pragma unroll
  for (int r = 0; r < 4; ++r) dg4[r] = (4 * g + r == c15) ? 1.f : 0.f;
  f32x4 L[2][2];
#pragma unroll
  for (int i = 0; i < 2; ++i)
#pragma unroll
    for (int j = 0; j < 2; ++j) L[i][j] = (f32x4){0.f, 0.f, 0.f, 0.f};
  for (int b = blockIdx.x; b < BATCH; b += gridDim.x)
    whiten_cheb<true>(x + (size_t)b * 1024, S_h, S_l, H, Lo, Bu, cof, g, c15, dg4, L);
#pragma unroll
  for (int i = 0; i < 2; ++i)
#pragma unroll
    for (int j = 0; j < 2; ++j)
#pragma unroll
      for (int r = 0; r < 4; ++r)
        atomicAdd(&wsf[OFF_LOGAVG + (16 * i + 4 * g + r) * 32 + 16 * j + c15], L[i][j][r]);
}

extern "C" __global__ void __launch_bounds__(64)
spdbn_kS2(float* __restrict__ wsf, const float* __restrict__ shift) {
  __shared__ alignas(16) float W0[32][LDSW], W1[32][LDSW], W2[32][LDSW], W3[32][LDSW], W4[32][LDSW];
  const int lane = threadIdx.x, h = lane >> 5, c = lane & 31;
#pragma unroll
  for (int i = 0; i < 16; ++i) {
    int r = 16 * h + i;
    W0[r][c] = wsf[OFF_LOGAVG + r * 32 + c] * (1.f / (float)BATCH);
    W1[r][c] = (r == c) ? 1.f : 0.f;
  }
  __syncthreads();
  for (int j = EXP_TERMS; j >= 1; --j) {
    mm64(W3, W0, W1, lane);
    const float inv = 1.f / (float)j;
#pragma unroll
    for (int i = 0; i < 16; ++i) {
      int r = 16 * h + i;
      W1[r][c] = ((r == c) ? 1.f : 0.f) + W3[r][c] * inv;
    }
    __syncthreads();
  }
#pragma unroll
  for (int i = 0; i < 16; ++i) { int r = 16 * h + i; W2[r][c] = wsf[OFF_S0 + r * 32 + c]; }
  __syncthreads();
  mm64(W3, W2, W1, lane);
  mm64(W0, W3, W2, lane);
  float tr = 0.f;
#pragma unroll
  for (int k = 0; k < 32; ++k) tr += W0[k][k];
  tr *= (1.f / 32.f);
  const float itr = 1.f / tr;
#pragma unroll
  for (int i = 0; i < 16; ++i) {
    int r = 16 * h + i;
    W1[r][c] = W0[r][c] * itr;
    W2[r][c] = (r == c) ? 1.f : 0.f;
  }
  __syncthreads();
  LdsMat Y = W1, Z = W2, Ya = W0, Za = W4;
  ns_sqrt(Y, Z, Ya, Za, W3, lane);
  const float rs = rsqrtf(tr);
#pragma unroll
  for (int i = 0; i < 16; ++i) { int r = 16 * h + i; wsf[OFF_INVS + r * 32 + c] = Z[r][c] * rs; }
  __syncthreads();
  float tr2 = 0.f;
#pragma unroll
  for (int k = 0; k < 32; ++k) tr2 += shift[33 * k];
  tr2 *= (1.f / 32.f);
  const float itr2 = 1.f / tr2;
#pragma unroll
  for (int i = 0; i < 16; ++i) {
    int r = 16 * h + i;
    W1[r][c] = shift[r * 32 + c] * itr2;
    W2[r][c] = (r == c) ? 1.f : 0.f;
  }
  __syncthreads();
  LdsMat Y2 = W1, Z2 = W2, Ya2 = W0, Za2 = W4;
  ns_sqrt(Y2, Z2, Ya2, Za2, W3, lane);
  const float sq2 = sqrtf(tr2);
#pragma unroll
  for (int i = 0; i < 16; ++i) { int r = 16 * h + i; wsf[OFF_SSQRT + r * 32 + c] = Y2[r][c] * sq2; }
}

// BN whiten: L_b = log(inv_s x_b inv_s) -> d_out (scratch); var += ||L_b||_F^2
extern "C" __global__ void __launch_bounds__(64, 4)
spdbn_kC(const float* __restrict__ x, float* __restrict__ wsf, float* __restrict__ outL) {
  __shared__ alignas(16) u16t H[32][40], Lo[32][40], Bu[32][40];
  const int lane = threadIdx.x;
  const int g = lane >> 4, c15 = lane & 15;
  short8 S_h[2], S_l[2];
  load_sym_frags(wsf + OFF_INVS, c15, g, S_h, S_l);
  const float* cof = wsf + OFF_CHEB;
  f32x4 dg4;
#pragma unroll
  for (int r = 0; r < 4; ++r) dg4[r] = (4 * g + r == c15) ? 1.f : 0.f;
  float ss = 0.f;
  f32x4 L[2][2];
  for (int b = blockIdx.x; b < BATCH; b += gridDim.x) {
    whiten_cheb<false>(x + (size_t)b * 1024, S_h, S_l, H, Lo, Bu, cof, g, c15, dg4, L);
    float* ob = outL + (size_t)b * 1024;
#pragma unroll
    for (int i = 0; i < 2; ++i)
#pragma unroll
      for (int j = 0; j < 2; ++j)
#pragma unroll
        for (int r = 0; r < 4; ++r) {
          float v = L[i][j][r];
          ob[(16 * i + 4 * g + r) * 32 + 16 * j + c15] = v;
          ss = fmaf(v, v, ss);
        }
  }
#pragma unroll
  for (int off = 32; off >= 1; off >>= 1) ss += __shfl_xor(ss, off);
  if (lane == 0) atomicAdd(&wsf[OFF_VAR], ss);
}

extern "C" __global__ void spdbn_kS3(float* __restrict__ wsf, const float* __restrict__ scale) {
  if (threadIdx.x == 0) {
    float var = wsf[OFF_VAR] * (1.f / (float)BATCH);
    float stdv = sqrtf(var);
    wsf[OFF_P] = scale[0] / (stdv + 1e-5f);
  }
}

// out = s_sqrt * exp(p*L) * s_sqrt  (reads L from d_out, overwrites in place)
extern "C" __global__ void __launch_bounds__(64, 5)
spdbn_kD(float* __restrict__ out, const float* __restrict__ wsf) {
  __shared__ alignas(16) u16t H[32][40], Lo[32][40], Bu[32][40];
  const int lane = threadIdx.x;
  const int g = lane >> 4, c15 = lane & 15;
  short8 Q_h[2], Q_l[2];
  load_sym_frags(wsf + OFF_SSQRT, c15, g, Q_h, Q_l);
  const float p = wsf[OFF_P];
  const f32x4 z4 = {0.f, 0.f, 0.f, 0.f};
  f32x4 dg4;
#pragma unroll
  for (int r = 0; r < 4; ++r) dg4[r] = (4 * g + r == c15) ? 1.f : 0.f;
  for (int b = blockIdx.x; b < BATCH; b += gridDim.x) {
    float* ob = out + (size_t)b * 1024;
    // M = p*L A-frags direct from global (L symmetric)
    short8 M_h[2], M_l[2];
#pragma unroll
    for (int t = 0; t < 2; ++t)
      ldsplit8(ob + (16 * t + c15) * 32 + 8 * g, p, M_h[t], M_l[t]);
    // Taylor: P = I; P = I + (M/jj)P  (single-bf16 B, ping-pong H <-> Bu)
    f32x4 Pv[2][2];
#pragma unroll
    for (int i = 0; i < 2; ++i)
#pragma unroll
      for (int j = 0; j < 2; ++j)
#pragma unroll
        for (int r = 0; r < 4; ++r) Pv[i][j][r] = (i == j) ? dg4[r] : 0.f;
    f32x4 acc[2][2];
#pragma unroll
    for (int jj = EXP_TERMS; jj >= 1; --jj) {
      const int t = EXP_TERMS - jj;
      u16t (*W)[40] = (t & 1) ? Bu : H;
#pragma unroll
      for (int i = 0; i < 2; ++i)
#pragma unroll
        for (int j = 0; j < 2; ++j)
          stg_single(W, 16 * j + c15, 16 * i + 4 * g, Pv[i][j]);
      __syncthreads();
      short8 B0 = fragr(W, 0, c15, g), B1 = fragr(W, 1, c15, g);
#pragma unroll
      for (int i = 0; i < 2; ++i) {
        f32x4 a = z4;
        a = MFMA16(M_l[i], B0, a);
        a = MFMA16(M_h[i], B0, a);
        acc[i][0] = a;
        f32x4 c = z4;
        c = MFMA16(M_l[i], B1, c);
        c = MFMA16(M_h[i], B1, c);
        acc[i][1] = c;
      }
      const float inv = 1.f / (float)jj;
#pragma unroll
      for (int i = 0; i < 2; ++i)
#pragma unroll
        for (int j = 0; j < 2; ++j)
#pragma unroll
          for (int r = 0; r < 4; ++r)
            Pv[i][j][r] = fmaf(acc[i][j][r], inv, (i == j) ? dg4[r] : 0.f);
      __syncthreads();
    }
    // W = P * Ssq   (P symmetric -> A-frags from split staging)
#pragma unroll
    for (int i = 0; i < 2; ++i)
#pragma unroll
      for (int j = 0; j < 2; ++j)
        stg_split(H, Lo, 16 * j + c15, 16 * i + 4 * g, Pv[i][j]);
    __syncthreads();
    short8 Ph[2], Pl[2];
#pragma unroll
    for (int t = 0; t < 2; ++t) { Ph[t] = fragr(H, t, c15, g); Pl[t] = fragr(Lo, t, c15, g); }
#pragma unroll
    for (int i = 0; i < 2; ++i)
#pragma unroll
      for (int j = 0; j < 2; ++j) {
        f32x4 a = z4;
        a = MFMA16(Pl[i], Q_h[j], a);
        a = MFMA16(Ph[i], Q_l[j], a);
        a = MFMA16(Ph[i], Q_h[j], a);
        acc[i][j] = a;
      }
    __syncthreads();
#pragma unroll
    for (int i = 0; i < 2; ++i)
#pragma unroll
      for (int j = 0; j < 2; ++j)
        stg_split(H, Lo, 16 * j + c15, 16 * i + 4 * g, acc[i][j]);
    __syncthreads();
    short8 Wh[2], Wl[2];
#pragma unroll
    for (int j = 0; j < 2; ++j) { Wh[j] = fragr(H, j, c15, g); Wl[j] = fragr(Lo, j, c15, g); }
#pragma unroll
    for (int i = 0; i < 2; ++i)
#pragma unroll
      for (int j = 0; j < 2; ++j) {
        f32x4 a = z4;
        a = MFMA16(Q_l[i], Wh[j], a);
        a = MFMA16(Q_h[i], Wl[j], a);
        a = MFMA16(Q_h[i], Wh[j], a);
        acc[i][j] = a;
      }
#pragma unroll
    for (int i = 0; i < 2; ++i)
#pragma unroll
      for (int j = 0; j < 2; ++j)
#pragma unroll
        for (int r = 0; r < 4; ++r)
          ob[(16 * i + 4 * g + r) * 32 + 16 * j + c15] = acc[i][j][r];
    __syncthreads();
  }
}

extern "C" void kernel_launch(void* const* d_in, const int* in_sizes, int n_in,
                              void* d_out, int out_size, void* d_ws, size_t ws_size,
                              hipStream_t stream) {
  const float* x     = (const float*)d_in[0];
  const float* shift = (const float*)d_in[1];
  const float* scale = (const float*)d_in[2];
  float* out = (float*)d_out;
  float* wsf = (float*)d_ws;

  size_t zbytes = 32768;
  if (ws_size < zbytes) zbytes = ws_size;
  hipMemsetAsync(d_ws, 0, zbytes, stream);

  hipLaunchKernelGGL(spdbn_kA,  dim3(4096),   dim3(256), 0, stream, x, wsf);
  hipLaunchKernelGGL(spdbn_kS1, dim3(1),      dim3(64),  0, stream, wsf);
  hipLaunchKernelGGL(spdbn_kB,  dim3(GRID_B), dim3(64),  0, stream, x, wsf);
  hipLaunchKernelGGL(spdbn_kS2, dim3(1),      dim3(64),  0, stream, wsf, shift);
  hipLaunchKernelGGL(spdbn_kC,  dim3(GRID_C), dim3(64),  0, stream, x, wsf, out);
  hipLaunchKernelGGL(spdbn_kS3, dim3(1),      dim3(64),  0, stream, wsf, scale);
  hipLaunchKernelGGL(spdbn_kD,  dim3(GRID_D), dim3(64),  0, stream, out, wsf);
}